// Round 4
// baseline (85.341 us; speedup 1.0000x reference)
//
#include <hip/hip_runtime.h>
#include <math.h>

// B=8192, D=128, NUM_CLASSES=512, MARGIN=0.2
#define BATCH 8192
#define DIM 128
#define MARGIN_F 0.2f
#define NCLS 512
#define MAXM 64          // max members per class staged (expected ~16, max ~40)

#define NCHUNK 8         // column chunks for mining
#define CHW 1024         // cols per chunk
#define BT 64            // cols per staged B-tile (16 KB per buffer)
#define NT (CHW / BT)    // tiles per chunk = 16
#define NBLK2 ((BATCH / 128) * NCHUNK)   // 512 mining blocks

typedef _Float16 f16x8 __attribute__((ext_vector_type(8)));
typedef _Float16 f16x2 __attribute__((ext_vector_type(2)));
typedef float    f32x4 __attribute__((ext_vector_type(4)));

// ================= K1: fused normalize/pack (blocks 0..2047) + per-class d_ap (blocks 2048..2559) =================
__global__ __launch_bounds__(256) void tl_prep(const float* __restrict__ emb,
                                               const int* __restrict__ labels,
                                               unsigned short* __restrict__ eP16,
                                               float* __restrict__ dapA,
                                               unsigned int* __restrict__ gctr) {
    __shared__ float Lrow[MAXM][DIM + 4];   // +4 pad: row stride 132 words -> conflict-free row reads
    __shared__ unsigned int minU[MAXM];
    __shared__ float linv[MAXM];
    __shared__ int   lidx[MAXM];
    __shared__ int   lcnt;

    const int blk = blockIdx.x;
    const int tid = threadIdx.x;

    if (blk < BATCH / 4) {
        // ---- prep path: normalize 4 rows, pack fp16 pre-swizzled ----
        if (blk == 0 && tid == 0) atomicExch(gctr, 0u);
        int row = blk * 4 + (tid >> 6);
        int l   = tid & 63;
        float2 v = *reinterpret_cast<const float2*>(emb + (size_t)row * DIM + l * 2);
        float ss = v.x * v.x + v.y * v.y;
#pragma unroll
        for (int o = 32; o > 0; o >>= 1) ss += __shfl_xor(ss, o);
        float inv = 1.0f / fmaxf(sqrtf(ss), 1e-12f);
        f16x2 h;
        h[0] = (_Float16)(v.x * inv);
        h[1] = (_Float16)(v.y * inv);
        int ck  = l >> 2;                                // 16B chunk 0..15
        int off = ((ck ^ (row & 7)) * 16) + (l & 3) * 4; // XOR pre-swizzle
        *reinterpret_cast<f16x2*>((char*)eP16 + (size_t)row * 256 + off) = h;
        return;
    }

    // ---- class path: hardest positive for every member of class c ----
    const int c = blk - BATCH / 4;
    if (tid == 0) lcnt = 0;
    if (tid < MAXM) minU[tid] = 0xFFFFFFFFu;   // +inf sentinel in monotone-uint space
    __syncthreads();

#pragma unroll
    for (int k = 0; k < BATCH / 256; ++k) {
        int idx = tid + k * 256;
        if (labels[idx] == c) {
            int p = atomicAdd(&lcnt, 1);
            if (p < MAXM) lidx[p] = idx;
        }
    }
    __syncthreads();
    const int cnt = min(lcnt, MAXM);

    // stage member rows (4 threads per member) + inverse norms
    {
        int m = tid >> 2, q = tid & 3;
        float ss = 0.0f;
        if (m < cnt) {
            const float4* src = reinterpret_cast<const float4*>(emb + (size_t)lidx[m] * DIM) + q * 8;
#pragma unroll
            for (int u8 = 0; u8 < 8; ++u8) {
                float4 v = src[u8];
                *reinterpret_cast<float4*>(&Lrow[m][q * 32 + u8 * 4]) = v;
                ss += v.x * v.x + v.y * v.y + v.z * v.z + v.w * v.w;
            }
        }
        ss += __shfl_xor(ss, 1);
        ss += __shfl_xor(ss, 2);
        if (m < cnt && q == 0) linv[m] = 1.0f / fmaxf(sqrtf(ss), 1e-12f);
    }
    __syncthreads();

    // all-pairs min dot per member (min is order-invariant -> deterministic)
    const int P = cnt * cnt;
    for (int p = tid; p < P; p += 256) {
        int i = p / cnt, j = p - i * cnt;
        if (i != j) {
            const float4* ra = reinterpret_cast<const float4*>(&Lrow[i][0]);
            const float4* rb = reinterpret_cast<const float4*>(&Lrow[j][0]);
            float acc = 0.0f;
#pragma unroll
            for (int u8 = 0; u8 < 32; ++u8) {
                float4 a = ra[u8], b = rb[u8];
                acc += a.x * b.x + a.y * b.y + a.z * b.z + a.w * b.w;
            }
            float dm = acc * linv[i] * linv[j];
            unsigned u   = __float_as_uint(dm);
            unsigned key = (u >> 31) ? ~u : (u | 0x80000000u);   // monotone map
            atomicMin(&minU[i], key);
        }
    }
    __syncthreads();

    if (tid < cnt) {
        float dap = -INFINITY;
        if (cnt >= 2) {
            unsigned key = minU[tid];
            unsigned u   = (key & 0x80000000u) ? (key & 0x7FFFFFFFu) : ~key;
            float md = __uint_as_float(u);
            dap = fmaxf(1.0f - md, 0.0f);
        }
        dapA[lidx[tid]] = dap;
    }
}

// ================= K2: MFMA mining + last-block finalize =================
__device__ __forceinline__ void stageB(const char* __restrict__ gtile, char* lds, int tid) {
    int wid = tid >> 6, lane = tid & 63;
#pragma unroll
    for (int i = 0; i < 4; ++i) {
        int off = i * 4096 + wid * 1024;   // wave-uniform LDS base; HW adds lane*16
        __builtin_amdgcn_global_load_lds(
            (const __attribute__((address_space(1))) unsigned int*)(gtile + off + lane * 16),
            (__attribute__((address_space(3))) unsigned int*)(lds + off),
            16, 0, 0);
    }
}

__global__ __launch_bounds__(256, 2) void tl_mine(const unsigned short* __restrict__ eP16,
                                                  const int* __restrict__ labels,
                                                  const float* __restrict__ dapA,
                                                  float* __restrict__ part,
                                                  unsigned int* __restrict__ gctr,
                                                  float* __restrict__ out) {
    __shared__ char  Bs[2][BT * 256];    // 32 KB double-buffered B tiles
    __shared__ float mkS[2][128];
    __shared__ int   isLast;

    const int tid = threadIdx.x;
    const int l   = tid & 63;
    const int wid = tid >> 6;
    const int wr  = wid >> 1, wc = wid & 1;   // 2x2 wave grid; wave tile 64 rows x 32 cols
    const int rb  = blockIdx.x >> 3;
    const int ch  = blockIdx.x & (NCHUNK - 1);
    const int rowBase = rb * 128;
    const int colBase = ch * CHW;
    const char* eP = (const char*)eP16;

    const int lo   = l & 15;
    const int kgrp = l >> 4;
    const int swz  = lo & 7;

    // A fragments in registers: 64 rows x K=128
    f16x8 af[4][4];
#pragma unroll
    for (int rf = 0; rf < 4; ++rf)
#pragma unroll
        for (int kc = 0; kc < 4; ++kc) {
            int row   = rowBase + wr * 64 + rf * 16 + lo;
            int chunk = (kc * 4 + kgrp) ^ swz;
            af[rf][kc] = *reinterpret_cast<const f16x8*>(eP + (size_t)row * 256 + chunk * 16);
        }

    // per-row mining state (C/D layout: col=lane&15, row=(lane>>4)*4+reg)
    float wCen[16]; int la[16]; float mk[16];
#pragma unroll
    for (int rf = 0; rf < 4; ++rf)
#pragma unroll
        for (int i = 0; i < 4; ++i) {
            int r = rowBase + wr * 64 + rf * 16 + kgrp * 4 + i;
            float draw = dapA[r];
            float ds   = (draw > -1e30f) ? draw : 0.0f;
            wCen[rf * 4 + i] = (1.0f - ds) - 0.5f * MARGIN_F;  // window center in dot space
            la[rf * 4 + i]   = labels[r];
            mk[rf * 4 + i]   = -INFINITY;
        }

    stageB(eP + (size_t)colBase * 256, Bs[0], tid);
    __syncthreads();

    int cur = 0;
    for (int t = 0; t < NT; ++t) {
        if (t + 1 < NT) stageB(eP + (size_t)(colBase + (t + 1) * BT) * 256, Bs[cur ^ 1], tid);

        f32x4 acc[4][2];
#pragma unroll
        for (int rf = 0; rf < 4; ++rf)
#pragma unroll
            for (int cf = 0; cf < 2; ++cf) {
                acc[rf][cf][0] = 0.0f; acc[rf][cf][1] = 0.0f;
                acc[rf][cf][2] = 0.0f; acc[rf][cf][3] = 0.0f;
            }

#pragma unroll
        for (int kc = 0; kc < 4; ++kc) {
            f16x8 bf[2];
#pragma unroll
            for (int cf = 0; cf < 2; ++cf) {
                int rr    = wc * 32 + cf * 16 + lo;
                int chunk = (kc * 4 + kgrp) ^ (rr & 7);
                bf[cf] = *reinterpret_cast<const f16x8*>(&Bs[cur][rr * 256 + chunk * 16]);
            }
#pragma unroll
            for (int rf = 0; rf < 4; ++rf)
#pragma unroll
                for (int cf = 0; cf < 2; ++cf)
                    acc[rf][cf] = __builtin_amdgcn_mfma_f32_16x16x32_f16(
                        af[rf][kc], bf[cf], acc[rf][cf], 0, 0, 0);
        }

        // fused mining epilogue (dot space, single key)
        int lbB[2];
#pragma unroll
        for (int cf = 0; cf < 2; ++cf)
            lbB[cf] = labels[colBase + t * BT + wc * 32 + cf * 16 + lo];
#pragma unroll
        for (int rf = 0; rf < 4; ++rf)
#pragma unroll
            for (int i = 0; i < 4; ++i) {
                int ri = rf * 4 + i;
                float cen = wCen[ri];
                int   lr  = la[ri];
                float d0  = acc[rf][0][i];
                float d1  = acc[rf][1][i];
                bool  w0  = fabsf(d0 - cen) < (0.5f * MARGIN_F);
                bool  w1  = fabsf(d1 - cen) < (0.5f * MARGIN_F);
                float k0  = w0 ? d0 : d0 - 4.0f;
                float k1  = w1 ? d1 : d1 - 4.0f;
                k0 = (lbB[0] != lr) ? k0 : -INFINITY;
                k1 = (lbB[1] != lr) ? k1 : -INFINITY;
                mk[ri] = fmaxf(mk[ri], fmaxf(k0, k1));   // -> v_max3_f32
            }
        __syncthreads();
        cur ^= 1;
    }

    // reduce across the 16 lanes sharing rows
#pragma unroll
    for (int m = 1; m < 16; m <<= 1)
#pragma unroll
        for (int r16 = 0; r16 < 16; ++r16)
            mk[r16] = fmaxf(mk[r16], __shfl_xor(mk[r16], m));
    if ((l & 15) == 0) {
#pragma unroll
        for (int rf = 0; rf < 4; ++rf)
#pragma unroll
            for (int i = 0; i < 4; ++i)
                mkS[wc][wr * 64 + rf * 16 + kgrp * 4 + i] = mk[rf * 4 + i];
    }
    __syncthreads();
    if (tid < 128)
        part[(size_t)ch * BATCH + rowBase + tid] = fmaxf(mkS[0][tid], mkS[1][tid]);

    // ---- last-block finalize ----
    __threadfence();           // release part stores (device scope)
    __syncthreads();
    if (tid == 0) {
        unsigned old = atomicAdd(gctr, 1u);
        isLast = (old == NBLK2 - 1);
    }
    __syncthreads();
    if (!isLast) return;
    __threadfence();           // acquire

    float s = 0.0f, cc = 0.0f;
    for (int r = tid; r < BATCH; r += 256) {
        float draw = dapA[r];
        float mkv  = part[r];
#pragma unroll
        for (int chh = 1; chh < NCHUNK; ++chh)
            mkv = fmaxf(mkv, part[(size_t)chh * BATCH + r]);
        bool hasPos = draw > -1e30f;
        bool hasNeg = mkv  > -1e30f;
        float dapv  = hasPos ? draw : 0.0f;
        bool  semi  = mkv > -2.0f;                 // in-window keys > -1.2; shifted keys < -3
        float dotAn = semi ? mkv : mkv + 4.0f;
        float dan   = fmaxf(1.0f - dotAn, 0.0f);
        if (hasPos && hasNeg) {
            s  += fmaxf(dapv - dan + MARGIN_F, 0.0f);
            cc += 1.0f;
        }
    }
#pragma unroll
    for (int o = 32; o > 0; o >>= 1) { s += __shfl_xor(s, o); cc += __shfl_xor(cc, o); }
    if ((tid & 63) == 0) { mkS[0][tid >> 6] = s; mkS[1][tid >> 6] = cc; }
    __syncthreads();
    if (tid == 0) {
        float S = mkS[0][0] + mkS[0][1] + mkS[0][2] + mkS[0][3];
        float C = mkS[1][0] + mkS[1][1] + mkS[1][2] + mkS[1][3];
        out[0] = S / fmaxf(C, 1.0f);
    }
}

extern "C" void kernel_launch(void* const* d_in, const int* in_sizes, int n_in,
                              void* d_out, int out_size, void* d_ws, size_t ws_size,
                              hipStream_t stream) {
    const float* emb    = (const float*)d_in[0];
    const int*   labels = (const int*)d_in[1];
    float*       out    = (float*)d_out;

    char* ws = (char*)d_ws;
    unsigned short* eP16 = (unsigned short*)(ws);                          // 2 MB
    float*        dapA   = (float*)(ws + 2 * 1024 * 1024);                 // 32 KB
    float*        part   = (float*)(ws + 2 * 1024 * 1024 + 32 * 1024);     // 256 KB
    unsigned int* gctr   = (unsigned int*)(ws + 2 * 1024 * 1024 + 512 * 1024);

    tl_prep<<<BATCH / 4 + NCLS, 256, 0, stream>>>(emb, labels, eP16, dapA, gctr);
    tl_mine<<<NBLK2, 256, 0, stream>>>(eP16, labels, dapA, part, gctr, out);
}